// Round 11
// baseline (193.090 us; speedup 1.0000x reference)
//
#include <hip/hip_runtime.h>
#include <hip/hip_bf16.h>
#include <math.h>

// Attention_10840497455414: x[8,1024,768] fp32 -> QKV -> 12-head attention ->
// proj+bias -> fp32 out. Compute in bf16 MFMA, fp32 accumulation.
//
// Pipeline (intermediates bf16 in d_ws). 4 launches:
//   0) convert3  : one kernel converts x, w_qkv, w_proj fp32->bf16
//   1) qkv_gemm  : [8192,768] x [2304,768]^T -> Q(scaled by 1/8*log2e)/K/Vt
//   2) attn v7   : 64-key LDS tiles (16 KB total -- occupancy evidence says
//                  the workgroup LDS pool is ~64KB/CU: 32KB kernels pin at
//                  2 blocks/CU, v6's 50KB ran at 1 block/CU). P kept in
//                  REGISTERS: S^T C-layout == A-frag layout of 16x16x16 MFMA,
//                  so QK->exp2->PV is register-only (pbuf + fences deleted).
//   3) proj_gemm : M128xN64 tiles.
// R4 lesson: launch_bounds waves-arg too high -> 32-VGPR cap -> 1GB spill.

typedef unsigned short u16;
typedef __attribute__((ext_vector_type(8))) short bf16x8;   // 8 bf16 = 4 VGPRs
typedef __attribute__((ext_vector_type(4))) short bf16x4;   // 4 bf16 = 2 VGPRs
typedef __attribute__((ext_vector_type(4))) float f32x4;    // MFMA C/D
typedef __attribute__((ext_vector_type(4))) unsigned int u32x4;

#define MFMA_BF16(a, b, c) __builtin_amdgcn_mfma_f32_16x16x32_bf16((a), (b), (c), 0, 0, 0)

#if __has_builtin(__builtin_amdgcn_mfma_f32_16x16x16bf16_1k)
#define MFMA16_BF16(a, b, c) __builtin_amdgcn_mfma_f32_16x16x16bf16_1k((a), (b), (c), 0, 0, 0)
#else
static __device__ __forceinline__ f32x4 MFMA16_BF16(bf16x4 a, bf16x4 b, f32x4 c) {
  f32x4 d;
  asm volatile("v_mfma_f32_16x16x16_bf16 %0, %1, %2, %3"
               : "=v"(d) : "v"(a), "v"(b), "v"(c));
  return d;
}
#endif

static __device__ __forceinline__ void gld_lds16(const void* g, void* l) {
  __builtin_amdgcn_global_load_lds(
      (__attribute__((address_space(1))) void*)(g),
      (__attribute__((address_space(3))) void*)(l), 16, 0, 0);
}

static __device__ __forceinline__ u16 f2bf(float f) {
  __hip_bfloat16 h = __float2bfloat16(f);
  return *(u16*)&h;
}

static __device__ __forceinline__ float fast_exp2(float x) {
#if __has_builtin(__builtin_amdgcn_exp2f)
  return __builtin_amdgcn_exp2f(x);   // raw v_exp_f32 (D = 2^S0)
#else
  return exp2f(x);
#endif
}

// fp32 -> bf16 (RNE), non-finite sanitized to 0. 4 elems per thread.
static __device__ __forceinline__ void conv4(const float* src, u16* dst, int i) {
  const float4 v = *(const float4*)(src + i);
  float f0 = v.x, f1 = v.y, f2 = v.z, f3 = v.w;
  if (!isfinite(f0)) f0 = 0.f;
  if (!isfinite(f1)) f1 = 0.f;
  if (!isfinite(f2)) f2 = 0.f;
  if (!isfinite(f3)) f3 = 0.f;
  ushort4 o;
  o.x = f2bf(f0); o.y = f2bf(f1); o.z = f2bf(f2); o.w = f2bf(f3);
  *(ushort4*)(dst + i) = o;
}

// one launch for all three conversions (x: 6144 blocks, wq: 1728, wp: 576)
__global__ __launch_bounds__(256) void convert3_kernel(
    const float* __restrict__ x,  u16* __restrict__ xb,
    const float* __restrict__ wq, u16* __restrict__ wqb,
    const float* __restrict__ wp, u16* __restrict__ wpb)
{
  const int blk = blockIdx.x;
  if (blk < 6144)      conv4(x,  xb,  (blk * 256 + threadIdx.x) * 4);
  else if (blk < 7872) conv4(wq, wqb, ((blk - 6144) * 256 + threadIdx.x) * 4);
  else                 conv4(wp, wpb, ((blk - 7872) * 256 + threadIdx.x) * 4);
}

// ---------------------------------------------------------------------------
// GEMM core: C[m0..+128][n0..+128] = sum_k A[m][k]*B[n][k], K=768 (B^T form).
// 256 threads = 4 waves (2x2); each wave: 64x64 = 4x4 C-frags.
// LDS tiles 128x64 bf16 staged via global_load_lds, XOR chunk swizzle.
// ---------------------------------------------------------------------------
__device__ __forceinline__ void gemm_tile_768(
    const u16* __restrict__ A, const u16* __restrict__ B,
    int m0, int n0, u16* ldsA, u16* ldsB, f32x4 acc[4][4])
{
  const int tid  = threadIdx.x;
  const int lane = tid & 63;
  const int wave = tid >> 6;
  const int quad = lane >> 4;
  const int l16  = lane & 15;
  const int wm = wave >> 1, wn = wave & 1;

  const u16* gA[4]; const u16* gB[4]; int ldsoff[4];
#pragma unroll
  for (int it = 0; it < 4; ++it) {
    const int c   = it * 256 + tid;        // flat 16B-chunk id, 1024 per tile
    const int row = c >> 3;
    const int cc  = (c & 7) ^ (row & 7);   // global chunk stored at slot c&7
    gA[it] = A + (size_t)(m0 + row) * 768 + cc * 8;
    gB[it] = B + (size_t)(n0 + row) * 768 + cc * 8;
    ldsoff[it] = (it * 256 + wave * 64) * 8;  // wave-uniform; HW adds lane*16B
  }

  for (int kt = 0; kt < 12; ++kt) {          // BK = 64, 768/64 = 12
    __syncthreads();
#pragma unroll
    for (int it = 0; it < 4; ++it) {
      gld_lds16(gA[it] + kt * 64, ldsA + ldsoff[it]);
      gld_lds16(gB[it] + kt * 64, ldsB + ldsoff[it]);
    }
    __syncthreads();
#pragma unroll
    for (int kc = 0; kc < 2; ++kc) {          // two K=32 MFMA chunks
      bf16x8 av[4], bv[4];
#pragma unroll
      for (int i = 0; i < 4; ++i) {
        const int rowA = wm * 64 + i * 16 + l16;
        av[i] = *(const bf16x8*)(ldsA + rowA * 64 + (((kc * 4 + quad) ^ (rowA & 7)) * 8));
        const int rowB = wn * 64 + i * 16 + l16;
        bv[i] = *(const bf16x8*)(ldsB + rowB * 64 + (((kc * 4 + quad) ^ (rowB & 7)) * 8));
      }
#pragma unroll
      for (int i = 0; i < 4; ++i)
#pragma unroll
        for (int j = 0; j < 4; ++j)
          acc[i][j] = MFMA_BF16(av[i], bv[j], acc[i][j]);
    }
  }
}

// C/D layout (m89/m91): within a 16x16 frag, row(m) = quad*4+reg, col(n) = lane&15.

// QKV GEMM with LDS-transposed coalesced epilogue. 768/128=6 => each n-block
// is entirely Q, K, or V (which = bx/6) and covers exactly 2 heads.
__global__ __launch_bounds__(256, 4) void qkv_gemm_kernel(
    const u16* __restrict__ X, const u16* __restrict__ W,
    u16* __restrict__ Qb, u16* __restrict__ Kb, u16* __restrict__ Vt)
{
  __shared__ alignas(16) u16 lds[2 * 128 * 64];    // 32 KB: GEMM tiles, then ep
  u16* ldsA = lds;
  u16* ldsB = lds + 128 * 64;
  const int n0 = blockIdx.x * 128;   // 0..2176
  const int m0 = blockIdx.y * 128;   // 0..8064
  f32x4 acc[4][4];
  const f32x4 zero = {0.f, 0.f, 0.f, 0.f};
#pragma unroll
  for (int i = 0; i < 4; ++i)
#pragma unroll
    for (int j = 0; j < 4; ++j) acc[i][j] = zero;

  gemm_tile_768(X, W, m0, n0, ldsA, ldsB, acc);

  const int tid = threadIdx.x, lane = tid & 63, wave = tid >> 6;
  const int quad = lane >> 4, l16 = lane & 15;
  const int wm = wave >> 1, wn = wave & 1;

  const int which = blockIdx.x / 6;        // 0=Q 1=K 2=V (uniform per block)
  const bool isV = (which == 2);
  // Q scale: 64^-0.5 * log2(e) folded (attn uses exp2)
  const float sc = (which == 0) ? 0.180336880f : 1.0f;
  u16* ep = lds;                           // 128x128 bf16 view

  __syncthreads();                         // K-loop LDS frag reads done
#pragma unroll
  for (int i = 0; i < 4; ++i)
#pragma unroll
    for (int j = 0; j < 4; ++j)
#pragma unroll
      for (int r = 0; r < 4; ++r) {
        const int m_l = wm * 64 + i * 16 + quad * 4 + r;   // token-local
        const int o_l = wn * 64 + j * 16 + l16;            // feat-local
        const int row = isV ? o_l : m_l;
        const int col = isV ? m_l : o_l;
        const int ch  = col >> 3;
        const int chs = (ch & 8) | ((ch & 7) ^ (row & 7));
        ep[row * 128 + chs * 8 + (col & 7)] = f2bf(acc[i][j][r] * sc);
      }
  __syncthreads();

  // coalesced store: thread -> (row, half); 8 x dwordx4 = 128B per thread
  const int row  = tid >> 1, half = tid & 1;
  const int b_   = m0 >> 10;               // batch (1024 % 128 == 0)
  const int nb   = m0 & 1023;              // token base within batch
  const int oc0  = n0 - which * 768;       // feat base within segment
  u16* dst;
  if (!isV) {
    const int h = (oc0 >> 6) + half;       // 2 heads per block
    dst = (which == 0 ? Qb : Kb) + (((size_t)(b_ * 12 + h)) * 1024 + nb + row) * 64;
  } else {
    const int h = (oc0 >> 6) + (row >> 6);
    const int d = row & 63;
    dst = Vt + (((size_t)(b_ * 12 + h)) * 64 + d) * 1024 + nb + half * 64;
  }
#pragma unroll
  for (int c = 0; c < 8; ++c) {
    const int chs = half * 8 + (c ^ (row & 7));
    *(u32x4*)(dst + c * 8) = *(const u32x4*)(ep + row * 128 + chs * 8);
  }
}

// Proj GEMM: M128 x N64 tiles -> grid (12,64) = 768 blocks.
__global__ __launch_bounds__(256, 4) void proj_gemm_kernel(
    const u16* __restrict__ A, const u16* __restrict__ W,
    const float* __restrict__ bias, float* __restrict__ out)
{
  __shared__ alignas(16) u16 ldsA[128 * 64];   // [m][k] 16 KB
  __shared__ alignas(16) u16 ldsB[64 * 64];    // [n][k]  8 KB
  const int n0 = blockIdx.x * 64;
  const int m0 = blockIdx.y * 128;
  const int tid = threadIdx.x, lane = tid & 63, wave = tid >> 6;
  const int quad = lane >> 4, l16 = lane & 15;

  const u16* gA[4]; const u16* gB[2]; int loA[4], loB[2];
#pragma unroll
  for (int it = 0; it < 4; ++it) {
    const int c = it * 256 + tid, row = c >> 3, cc = (c & 7) ^ (row & 7);
    gA[it] = A + (size_t)(m0 + row) * 768 + cc * 8;
    loA[it] = (it * 256 + wave * 64) * 8;
  }
#pragma unroll
  for (int it = 0; it < 2; ++it) {
    const int c = it * 256 + tid, row = c >> 3, cc = (c & 7) ^ (row & 7);
    gB[it] = W + (size_t)(n0 + row) * 768 + cc * 8;
    loB[it] = (it * 256 + wave * 64) * 8;
  }

  f32x4 acc[2][4];
  const f32x4 zero = {0.f, 0.f, 0.f, 0.f};
#pragma unroll
  for (int s = 0; s < 2; ++s)
#pragma unroll
    for (int t = 0; t < 4; ++t) acc[s][t] = zero;

  for (int kt = 0; kt < 12; ++kt) {
    __syncthreads();
#pragma unroll
    for (int it = 0; it < 4; ++it) gld_lds16(gA[it] + kt * 64, ldsA + loA[it]);
#pragma unroll
    for (int it = 0; it < 2; ++it) gld_lds16(gB[it] + kt * 64, ldsB + loB[it]);
    __syncthreads();
#pragma unroll
    for (int kc = 0; kc < 2; ++kc) {
      bf16x8 av[2], bv[4];
#pragma unroll
      for (int s = 0; s < 2; ++s) {
        const int rowA = wave * 32 + s * 16 + l16;
        av[s] = *(const bf16x8*)(ldsA + rowA * 64 + (((kc * 4 + quad) ^ (rowA & 7)) * 8));
      }
#pragma unroll
      for (int t = 0; t < 4; ++t) {
        const int rowB = t * 16 + l16;
        bv[t] = *(const bf16x8*)(ldsB + rowB * 64 + (((kc * 4 + quad) ^ (rowB & 7)) * 8));
      }
#pragma unroll
      for (int s = 0; s < 2; ++s)
#pragma unroll
        for (int t = 0; t < 4; ++t)
          acc[s][t] = MFMA_BF16(av[s], bv[t], acc[s][t]);
    }
  }

  float bv4[4];
#pragma unroll
  for (int t = 0; t < 4; ++t) bv4[t] = bias[n0 + t * 16 + l16];
#pragma unroll
  for (int s = 0; s < 2; ++s)
#pragma unroll
    for (int t = 0; t < 4; ++t)
#pragma unroll
      for (int r = 0; r < 4; ++r) {
        const int m = m0 + wave * 32 + s * 16 + quad * 4 + r;
        out[(size_t)m * 768 + n0 + t * 16 + l16] = acc[s][t][r] + bv4[t];
      }
}

// Attention v7: grid (96 heads, 8 q-blocks of 128), 256 threads = 4 waves,
// each wave 32 queries (2 strips of 16), full 1024-key sweep.
// 64-key tiles: K[64,64] (8KB) + Vt[64,64-key slice] (8KB) = 16 KB LDS.
// QK as S^T (A=K, B=Q, 16x16x32): lane(q=l16, quad) gets keys quad*4+r --
// which IS the A-frag layout of v_mfma_f32_16x16x16_bf16 (k=quad*4+j), so
// exp2(S^T) packs straight into PV A-frags: NO LDS round-trip for P.
// PV: O[q][d] += sum_t P_t(16 keys) x V_t via 16x16x16; V B-frags are b64
// reads from ldsV rows (n=d=l16, k=quad*4+j).
__global__ __launch_bounds__(256, 3) void attn_kernel(
    const u16* __restrict__ Q, const u16* __restrict__ K,
    const u16* __restrict__ Vt, __hip_bfloat16* __restrict__ O)
{
  __shared__ alignas(16) u16 ldsK[64 * 64];    // 8 KB: keys x d
  __shared__ alignas(16) u16 ldsV[64 * 64];    // 8 KB: d x keys (64-key slice)
  const int bh = blockIdx.x;     // b*12 + h
  const int qb = blockIdx.y;     // 128-query block
  const int tid = threadIdx.x;
  const int wave = tid >> 6, lane = tid & 63;
  const int quad = lane >> 4, l16 = lane & 15;

  const int q0 = qb * 128 + wave * 32;
  const u16* Kbh = K  + (size_t)bh * (1024 * 64);
  const u16* Vbh = Vt + (size_t)bh * (64 * 1024);

  // staging: 2 issues K + 2 issues V per 64-key tile (2 x 256 x 16B = 8KB ea)
  const u16* gK[2]; const u16* gV[2]; int lo[2];
#pragma unroll
  for (int it = 0; it < 2; ++it) {
    const int c = it * 256 + tid;
    const int row = c >> 3, cc = (c & 7) ^ (row & 7);
    gK[it] = Kbh + (size_t)row * 64 + cc * 8;     // row = key 0..63
    gV[it] = Vbh + (size_t)row * 1024 + cc * 8;   // row = d   0..63
    lo[it] = (it * 256 + wave * 64) * 8;
  }

  // Q frags (B[n=q=l16][k=quad*8+j]), resident for the whole loop
  bf16x8 aQ0[2], aQ1[2];
#pragma unroll
  for (int s = 0; s < 2; ++s) {
    const u16* qp = Q + ((size_t)bh * 1024 + q0 + s * 16 + l16) * 64 + quad * 8;
    aQ0[s] = *(const bf16x8*)qp;
    aQ1[s] = *(const bf16x8*)(qp + 32);
  }

  f32x4 oacc[2][4];
  const f32x4 zero = {0.f, 0.f, 0.f, 0.f};
#pragma unroll
  for (int s = 0; s < 2; ++s)
#pragma unroll
    for (int db = 0; db < 4; ++db) oacc[s][db] = zero;
  float lacc[2] = {0.f, 0.f};    // per-lane denom partial for query (s, l16)

  for (int kt = 0; kt < 16; ++kt) {       // 16 tiles of 64 keys
    __syncthreads();                      // prev tile's LDS reads done
#pragma unroll
    for (int it = 0; it < 2; ++it) {
      gld_lds16(gK[it] + (size_t)kt * 64 * 64, ldsK + lo[it]);
      gld_lds16(gV[it] + kt * 64, ldsV + lo[it]);
    }
    __syncthreads();                      // vmcnt drained -> staging visible

    // K frags (A[m=key][k=quad*8+j]) from LDS, shared by all waves
    bf16x8 kb0[4], kb1[4];
#pragma unroll
    for (int t = 0; t < 4; ++t) {
      const int row = t * 16 + l16;
      kb0[t] = *(const bf16x8*)(ldsK + row * 64 + (((0 * 4 + quad) ^ (row & 7)) * 8));
      kb1[t] = *(const bf16x8*)(ldsK + row * 64 + (((1 * 4 + quad) ^ (row & 7)) * 8));
    }
    // S^T = K Q^T -> p = exp2 -> PV A-frags in registers
    bf16x4 pa[2][4];
#pragma unroll
    for (int s = 0; s < 2; ++s) {
#pragma unroll
      for (int t = 0; t < 4; ++t) {
        f32x4 z = zero;
        z = MFMA_BF16(kb0[t], aQ0[s], z);
        z = MFMA_BF16(kb1[t], aQ1[s], z);
        const float p0 = fast_exp2(z[0]);
        const float p1 = fast_exp2(z[1]);
        const float p2 = fast_exp2(z[2]);
        const float p3 = fast_exp2(z[3]);
        lacc[s] += (p0 + p1) + (p2 + p3);
        bf16x4 pk;
        pk[0] = (short)f2bf(p0); pk[1] = (short)f2bf(p1);
        pk[2] = (short)f2bf(p2); pk[3] = (short)f2bf(p3);
        pa[s][t] = pk;
      }
    }
    // O += P V via 16x16x16 (B[n=d=l16][k=key=quad*4+j], b64 reads)
#pragma unroll
    for (int db = 0; db < 4; ++db) {
      const int d = db * 16 + l16;
#pragma unroll
      for (int t = 0; t < 4; ++t) {
        const int slot = (t * 2 + (quad >> 1)) ^ (d & 7);
        const bf16x4 v = *(const bf16x4*)(ldsV + d * 64 + slot * 8 + (quad & 1) * 4);
#pragma unroll
        for (int s = 0; s < 2; ++s)
          oacc[s][db] = MFMA16_BF16(pa[s][t], v, oacc[s][db]);
      }
    }
  }

  // epilogue: full denom per query (s,l16) = quad-reduce; broadcast to the
  // oacc row layout (row=q=quad*4+r, col=d=l16) via shfl, write O.
  const int b = bh / 12, h = bh - (bh / 12) * 12;
  float linv[2];
#pragma unroll
  for (int s = 0; s < 2; ++s) {
    float l = lacc[s];
    l += __shfl_xor(l, 16);
    l += __shfl_xor(l, 32);
    linv[s] = 1.f / l;        // uniform across quads; indexed by l16
  }
#pragma unroll
  for (int s = 0; s < 2; ++s) {
#pragma unroll
    for (int r = 0; r < 4; ++r) {
      const float inv = __shfl(linv[s], quad * 4 + r);   // denom of query row
      const int n = q0 + s * 16 + quad * 4 + r;
      __hip_bfloat16* orow = O + ((size_t)b * 1024 + n) * 768 + h * 64;
#pragma unroll
      for (int db = 0; db < 4; ++db)
        orow[db * 16 + l16] = __float2bfloat16(oacc[s][db][r] * inv);
    }
  }
}

extern "C" void kernel_launch(void* const* d_in, const int* in_sizes, int n_in,
                              void* d_out, int out_size, void* d_ws, size_t ws_size,
                              hipStream_t stream) {
  const float* x      = (const float*)d_in[0];   // [8,1024,768] fp32
  const float* w_qkv  = (const float*)d_in[1];   // [2304,768]  fp32
  const float* w_proj = (const float*)d_in[2];   // [768,768]   fp32
  const float* b_proj = (const float*)d_in[3];   // [768]       fp32
  float* out = (float*)d_out;                    // [8,1024,768] fp32

  char* ws = (char*)d_ws;
  const size_t SEG = (size_t)96 * 1024 * 64 * sizeof(u16);  // 12.58 MB
  u16* xb   = (u16*)(ws + 0 * SEG);              // x as bf16 [8192,768]
  u16* Qb   = (u16*)(ws + 1 * SEG);
  u16* Kb   = (u16*)(ws + 2 * SEG);
  u16* AO   = (u16*)(ws + 3 * SEG);              // attn out [8192,768] bf16
  u16* Vt   = (u16*)(ws + 4 * SEG);              // V^T [B,H,D,N]
  u16* wqb  = (u16*)(ws + 5 * SEG);              // w_qkv bf16 (3.54 MB)
  u16* wpb  = (u16*)(ws + 5 * SEG + 3538944);    // w_proj bf16 (1.18 MB)

  convert3_kernel<<<8448, 256, 0, stream>>>(x, xb, w_qkv, wqb, w_proj, wpb);
  qkv_gemm_kernel<<<dim3(18, 64), 256, 0, stream>>>(xb, wqb, Qb, Kb, Vt);
  attn_kernel    <<<dim3(96, 8), 256, 0, stream>>>(Qb, Kb, Vt, (__hip_bfloat16*)AO);
  proj_gemm_kernel<<<dim3(12, 64), 256, 0, stream>>>(AO, wpb, b_proj, out);
}